// Round 1
// baseline (864.775 us; speedup 1.0000x reference)
//
#include <hip/hip_runtime.h>
#include <math.h>

#define LLEN 4096
#define CCH 128
#define DI 384
#define NST 4
#define SBN 6        // 3 directions x B=2
#define NB 2
#define LDXP 136     // R + 2N
#define FCH 512
#define NCHUNK 64
#define TSTEP 64     // NCHUNK*TSTEP == LLEN

__device__ __forceinline__ float wave_sum(float v) {
#pragma unroll
    for (int o = 32; o > 0; o >>= 1) v += __shfl_xor(v, o);
    return v;
}

// ---------------- LayerNorm over C=128, building x_in on the fly ----------------
__global__ __launch_bounds__(64) void prep_ln1(const float* __restrict__ x,
                                               const int* __restrict__ ridx,
                                               const float* __restrict__ g,
                                               const float* __restrict__ b,
                                               float* __restrict__ xn)
{
    int r = blockIdx.x;                  // 0 .. 6*L-1
    int sb = r / LLEN, l = r % LLEN;
    int s = sb >> 1, bb = sb & 1;        // concat order: [x(b0),x(b1),flip(b0),flip(b1),shf(b0),shf(b1)]
    int srcl = (s == 0) ? l : (s == 1 ? (LLEN - 1 - l) : ridx[l]);
    const float* src = x + ((size_t)bb * LLEN + srcl) * CCH;
    int lane = threadIdx.x;
    float v0 = src[lane], v1 = src[lane + 64];
    float m = wave_sum(v0 + v1) * (1.f / 128.f);
    float d0 = v0 - m, d1 = v1 - m;
    float var = wave_sum(d0 * d0 + d1 * d1) * (1.f / 128.f);
    float rstd = rsqrtf(var + 1e-5f);
    float* dst = xn + (size_t)r * CCH;
    dst[lane]      = d0 * rstd * g[lane]      + b[lane];
    dst[lane + 64] = d1 * rstd * g[lane + 64] + b[lane + 64];
}

// ---------------- Generic NT GEMM: C[M,N] = act(A[M,K] @ W[N,K]^T + bias) ----------------
// EPI: 0=none 1=bias 2=bias+softplus 3=bias+residual
template<int EPI>
__global__ __launch_bounds__(256) void gemm_nt(const float* __restrict__ A, int lda,
                                               const float* __restrict__ W,
                                               const float* __restrict__ bias,
                                               const float* __restrict__ res,
                                               float* __restrict__ Cc, int ldc,
                                               int M, int N, int Kd)
{
    __shared__ float As[32][33];
    __shared__ float Ws[32][33];
    int tid = threadIdx.x;
    int tx = tid & 31;     // n within tile
    int ty = tid >> 5;     // 0..7
    int bm = blockIdx.x * 32;
    int bn = blockIdx.y * 32;
    float acc[4] = {0.f, 0.f, 0.f, 0.f};
    for (int k0 = 0; k0 < Kd; k0 += 32) {
#pragma unroll
        for (int i = 0; i < 4; i++) {
            int r = ty + 8 * i;
            As[r][tx] = A[(size_t)(bm + r) * lda + k0 + tx];
            int n = bn + r;
            Ws[r][tx] = (n < N) ? W[(size_t)n * Kd + k0 + tx] : 0.f;
        }
        __syncthreads();
#pragma unroll
        for (int kk = 0; kk < 32; kk++) {
            float w = Ws[tx][kk];
#pragma unroll
            for (int i = 0; i < 4; i++)
                acc[i] = fmaf(As[ty + 8 * i][kk], w, acc[i]);
        }
        __syncthreads();
    }
    int n = bn + tx;
    if (n < N) {
#pragma unroll
        for (int i = 0; i < 4; i++) {
            int m = bm + ty + 8 * i;
            float v = acc[i];
            if (EPI == 1) v += bias[n];
            if (EPI == 2) { v += bias[n]; v = (v > 20.f) ? v : log1pf(expf(v)); }
            if (EPI == 3) { v += bias[n] + res[(size_t)m * ldc + n]; }
            Cc[(size_t)m * ldc + n] = v;
        }
    }
}

// ---------------- depthwise causal conv K=4 + bias + SiLU ----------------
__global__ __launch_bounds__(256) void dwconv_silu(const float* __restrict__ h,
                                                   const float* __restrict__ cw,
                                                   const float* __restrict__ cb,
                                                   float* __restrict__ u)
{
    int gid = blockIdx.x * 256 + threadIdx.x;   // total SBN*LLEN*DI
    int d = gid % DI;
    int row = gid / DI;
    int l = row % LLEN;
    float acc = cb[d];
#pragma unroll
    for (int k = 0; k < 4; k++) {
        int ls = l - 3 + k;
        if (ls >= 0) acc += cw[d * 4 + k] * h[(size_t)(row - l + ls) * DI + d];
    }
    u[(size_t)row * DI + d] = acc / (1.f + expf(-acc));
}

// ---------------- chunked selective scan ----------------
__global__ __launch_bounds__(DI) void scan_phaseA(const float* __restrict__ dt,
                                                  const float* __restrict__ xp,
                                                  const float* __restrict__ u,
                                                  const float* __restrict__ A_log,
                                                  float* __restrict__ P, float* __restrict__ S)
{
    int d = threadIdx.x;
    int chunk = blockIdx.x, sb = blockIdx.y;
    float a[NST];
#pragma unroll
    for (int n = 0; n < NST; n++) a[n] = -expf(A_log[d * NST + n]);
    float s[NST] = {0.f, 0.f, 0.f, 0.f}, p[NST] = {1.f, 1.f, 1.f, 1.f};
    int base = sb * LLEN + chunk * TSTEP;
    for (int t = 0; t < TSTEP; t++) {
        int row = base + t;
        float dtv = dt[(size_t)row * DI + d];
        float uv = u[(size_t)row * DI + d];
        float dtu = dtv * uv;
#pragma unroll
        for (int n = 0; n < NST; n++) {
            float dA = expf(dtv * a[n]);
            float Bv = xp[(size_t)row * LDXP + 128 + n];
            s[n] = dA * s[n] + dtu * Bv;
            p[n] *= dA;
        }
    }
    int idx = ((sb * NCHUNK + chunk) * DI + d) * NST;
#pragma unroll
    for (int n = 0; n < NST; n++) { P[idx + n] = p[n]; S[idx + n] = s[n]; }
}

__global__ __launch_bounds__(256) void scan_phaseB(const float* __restrict__ P,
                                                   const float* __restrict__ S,
                                                   float* __restrict__ I)
{
    int gid = blockIdx.x * 256 + threadIdx.x;
    if (gid >= SBN * DI * NST) return;
    int dn = gid % (DI * NST);
    int sb = gid / (DI * NST);
    float st = 0.f;
    for (int c = 0; c < NCHUNK; c++) {
        int idx = (sb * NCHUNK + c) * DI * NST + dn;
        I[idx] = st;
        st = P[idx] * st + S[idx];
    }
}

__global__ __launch_bounds__(DI) void scan_phaseC(const float* __restrict__ dt,
                                                  const float* __restrict__ xp,
                                                  const float* __restrict__ u,
                                                  const float* __restrict__ A_log,
                                                  const float* __restrict__ Dp,
                                                  const float* __restrict__ gate,
                                                  const float* __restrict__ I,
                                                  float* __restrict__ ymix)
{
    int d = threadIdx.x;
    int chunk = blockIdx.x, sb = blockIdx.y;
    float a[NST];
#pragma unroll
    for (int n = 0; n < NST; n++) a[n] = -expf(A_log[d * NST + n]);
    int idx = ((sb * NCHUNK + chunk) * DI + d) * NST;
    float s[NST];
#pragma unroll
    for (int n = 0; n < NST; n++) s[n] = I[idx + n];
    float Dv = Dp[d];
    int base = sb * LLEN + chunk * TSTEP;
    for (int t = 0; t < TSTEP; t++) {
        int row = base + t;
        float dtv = dt[(size_t)row * DI + d];
        float uv = u[(size_t)row * DI + d];
        float dtu = dtv * uv;
        float y = 0.f;
#pragma unroll
        for (int n = 0; n < NST; n++) {
            float dA = expf(dtv * a[n]);
            float Bv = xp[(size_t)row * LDXP + 128 + n];
            float Cv = xp[(size_t)row * LDXP + 132 + n];
            s[n] = dA * s[n] + dtu * Bv;
            y += s[n] * Cv;
        }
        float gt = gate[(size_t)row * DI + d];
        float sg = gt / (1.f + expf(-gt));
        ymix[(size_t)row * DI + d] = (y + uv * Dv) * sg;
    }
}

// ---------------- column means of y6 per (sb) ----------------
__global__ __launch_bounds__(256) void colmeans(const float* __restrict__ y6, float* __restrict__ means)
{
    int sb = blockIdx.x, rc = blockIdx.y;
    int c = threadIdx.x & 127, r0 = threadIdx.x >> 7;
    float ssum = 0.f;
    for (int r = rc * 256 + r0; r < rc * 256 + 256; r += 2)
        ssum += y6[((size_t)sb * LLEN + r) * CCH + c];
    __shared__ float red[128];
    if (r0) red[c] = ssum;
    __syncthreads();
    if (!r0) atomicAdd(&means[sb * CCH + c], ssum + red[c]);
}

__global__ __launch_bounds__(384) void gate_softmax(const float* __restrict__ means,
                                                    const float* __restrict__ gw,
                                                    float* __restrict__ g)
{
    int lane = threadIdx.x & 63, p = threadIdx.x >> 6;   // p = b*3+j
    int bb = p / 3, j = p % 3;
    float part = 0.f;
    for (int i = lane; i < 384; i += 64) {
        int s = i >> 7, c = i & 127;
        part += means[(s * 2 + bb) * 128 + c] * (1.f / 4096.f) * gw[j * 384 + i];
    }
    part = wave_sum(part);
    __shared__ float lg[6];
    if (lane == 0) lg[p] = part;
    __syncthreads();
    if (threadIdx.x < 2) {
        int b2 = threadIdx.x;
        float a0 = lg[b2 * 3], a1 = lg[b2 * 3 + 1], a2 = lg[b2 * 3 + 2];
        float mx = fmaxf(a0, fmaxf(a1, a2));
        float e0 = expf(a0 - mx), e1 = expf(a1 - mx), e2 = expf(a2 - mx);
        float inv = 1.f / (e0 + e1 + e2);
        g[b2 * 3] = e0 * inv; g[b2 * 3 + 1] = e1 * inv; g[b2 * 3 + 2] = e2 * inv;
    }
}

__global__ void make_inv(const int* __restrict__ ridx, int* __restrict__ inv)
{
    int l = blockIdx.x * blockDim.x + threadIdx.x;
    if (l < LLEN) inv[ridx[l]] = l;
}

// combine 3 directions + residual + LayerNorm2 (fused)
__global__ __launch_bounds__(64) void combine_ln2(const float* __restrict__ x,
                                                  const float* __restrict__ y6,
                                                  const float* __restrict__ g,
                                                  const int* __restrict__ inv,
                                                  const float* __restrict__ n2g,
                                                  const float* __restrict__ n2b,
                                                  float* __restrict__ x1,
                                                  float* __restrict__ xn2)
{
    int r = blockIdx.x;              // 0 .. 2*L-1
    int bb = r / LLEN, l = r % LLEN;
    int lane = threadIdx.x;
    float g0 = g[bb * 3 + 0], g1 = g[bb * 3 + 1], g2 = g[bb * 3 + 2];
    int il = inv[l];
    size_t fo = ((size_t)(0 + bb) * LLEN + l) * CCH;
    size_t ro = ((size_t)(2 + bb) * LLEN + (LLEN - 1 - l)) * CCH;
    size_t so = ((size_t)(4 + bb) * LLEN + il) * CCH;
    size_t xo = ((size_t)bb * LLEN + l) * CCH;
    float v0 = x[xo + lane]      + g0 * y6[fo + lane]      + g1 * y6[ro + lane]      + g2 * y6[so + lane];
    float v1 = x[xo + lane + 64] + g0 * y6[fo + lane + 64] + g1 * y6[ro + lane + 64] + g2 * y6[so + lane + 64];
    float m = wave_sum(v0 + v1) * (1.f / 128.f);
    float d0 = v0 - m, d1 = v1 - m;
    float var = wave_sum(d0 * d0 + d1 * d1) * (1.f / 128.f);
    float rstd = rsqrtf(var + 1e-5f);
    x1[xo + lane] = v0; x1[xo + lane + 64] = v1;
    xn2[xo + lane]      = d0 * rstd * n2g[lane]      + n2b[lane];
    xn2[xo + lane + 64] = d1 * rstd * n2g[lane + 64] + n2b[lane + 64];
}

// ---------------- 3x3 depthwise conv + exact GeLU (pixel-major, f contiguous) ----------------
__global__ __launch_bounds__(256) void peconv_gelu(const float* __restrict__ t,
                                                   const float* __restrict__ pw,
                                                   const float* __restrict__ pb,
                                                   float* __restrict__ t2)
{
    int gid = blockIdx.x * 256 + threadIdx.x;  // total 2*4096*512
    int f = gid & (FCH - 1);
    int pix = gid >> 9;
    int bb = pix >> 12;
    int l = pix & 4095;
    int h = l >> 6, w = l & 63;
    float acc = pb[f];
#pragma unroll
    for (int dy = -1; dy <= 1; dy++) {
        int hh = h + dy;
        if (hh < 0 || hh > 63) continue;
#pragma unroll
        for (int dx = -1; dx <= 1; dx++) {
            int ww = w + dx;
            if (ww < 0 || ww > 63) continue;
            acc += pw[f * 9 + (dy + 1) * 3 + (dx + 1)] * t[((size_t)(bb * 4096 + hh * 64 + ww)) * FCH + f];
        }
    }
    t2[(size_t)pix * FCH + f] = 0.5f * acc * (1.f + erff(acc * 0.70710678118654752f));
}

extern "C" void kernel_launch(void* const* d_in, const int* in_sizes, int n_in,
                              void* d_out, int out_size, void* d_ws, size_t ws_size,
                              hipStream_t stream)
{
    (void)in_sizes; (void)n_in; (void)ws_size;
    const float* x      = (const float*)d_in[0];
    const int*   ridx   = (const int*)d_in[1];
    const float* n1g    = (const float*)d_in[4];
    const float* n1b    = (const float*)d_in[5];
    const float* in_w   = (const float*)d_in[6];
    const float* conv_w = (const float*)d_in[7];
    const float* conv_b = (const float*)d_in[8];
    const float* xp_w   = (const float*)d_in[9];
    const float* dt_w   = (const float*)d_in[10];
    const float* dt_b   = (const float*)d_in[11];
    const float* A_log  = (const float*)d_in[12];
    const float* Dp     = (const float*)d_in[13];
    const float* out_w  = (const float*)d_in[14];
    const float* n2g    = (const float*)d_in[15];
    const float* n2b    = (const float*)d_in[16];
    const float* gate_w = (const float*)d_in[17];
    const float* fc1_w  = (const float*)d_in[18];
    const float* fc1_b  = (const float*)d_in[19];
    const float* pe_w   = (const float*)d_in[20];
    const float* pe_b   = (const float*)d_in[21];
    const float* fc2_w  = (const float*)d_in[22];
    const float* fc2_b  = (const float*)d_in[23];
    float* out = (float*)d_out;

    const size_t SZ_HD   = (size_t)SBN * LLEN * DI;     // 9437184
    const size_t SZ_XP   = (size_t)SBN * LLEN * LDXP;   // 3342336
    const size_t SZ_XN   = (size_t)SBN * LLEN * CCH;    // 3145728
    float* ws    = (float*)d_ws;
    float* hbuf  = ws;                 // h; later reused as dt
    float* gate  = hbuf + SZ_HD;
    float* u     = gate + SZ_HD;
    float* ymix  = u + SZ_HD;
    float* xpout = ymix + SZ_HD;
    float* xn    = xpout + SZ_XP;      // later P/S/I, then y6
    float* smallb = xn + SZ_XN;        // means(768) + g(6)
    int*   invb  = (int*)(smallb + 1024);
    // aliases (lifetimes verified: no overlap in time)
    float* dtb  = hbuf;                        // after dwconv consumed h
    float* P    = xn;                          // after in_proj consumed xn
    float* S    = xn + 589824;
    float* I    = xn + 1179648;
    float* y6   = xn;                          // after scan (P/S/I dead)
    float* x1   = u;                           // after scan (u dead)
    float* xn2  = u + (size_t)NB * LLEN * CCH;
    float* t    = gate;                        // after scan (gate dead)
    float* t2   = gate + (size_t)NB * LLEN * FCH;
    float* means = smallb;
    float* gbuf  = smallb + 768;

    const int M6 = SBN * LLEN;   // 24576
    const int M2 = NB * LLEN;    // 8192

    // 1) x_in construction + LN1
    prep_ln1<<<M6, 64, 0, stream>>>(x, ridx, n1g, n1b, xn);
    // 2) in_proj split into h and gate GEMMs
    gemm_nt<0><<<dim3(M6 / 32, DI / 32), 256, 0, stream>>>(xn, CCH, in_w, nullptr, nullptr, hbuf, DI, M6, DI, CCH);
    gemm_nt<0><<<dim3(M6 / 32, DI / 32), 256, 0, stream>>>(xn, CCH, in_w + (size_t)DI * CCH, nullptr, nullptr, gate, DI, M6, DI, CCH);
    // 3) depthwise causal conv + SiLU
    dwconv_silu<<<(M6 * DI) / 256, 256, 0, stream>>>(hbuf, conv_w, conv_b, u);
    // 4) x_proj
    gemm_nt<0><<<dim3(M6 / 32, (LDXP + 31) / 32), 256, 0, stream>>>(u, DI, xp_w, nullptr, nullptr, xpout, LDXP, M6, LDXP, DI);
    // 5) dt_proj + softplus (reads cols 0..127 of xpout)
    gemm_nt<2><<<dim3(M6 / 32, DI / 32), 256, 0, stream>>>(xpout, LDXP, dt_w, dt_b, nullptr, dtb, DI, M6, DI, CCH);
    // 6) chunked scan
    scan_phaseA<<<dim3(NCHUNK, SBN), DI, 0, stream>>>(dtb, xpout, u, A_log, P, S);
    scan_phaseB<<<(SBN * DI * NST + 255) / 256, 256, 0, stream>>>(P, S, I);
    scan_phaseC<<<dim3(NCHUNK, SBN), DI, 0, stream>>>(dtb, xpout, u, A_log, Dp, gate, I, ymix);
    // 7) out_proj
    gemm_nt<0><<<dim3(M6 / 32, CCH / 32), 256, 0, stream>>>(ymix, DI, out_w, nullptr, nullptr, y6, CCH, M6, CCH, DI);
    // 8) direction gating
    hipMemsetAsync(means, 0, 768 * sizeof(float), stream);
    colmeans<<<dim3(SBN, 16), 256, 0, stream>>>(y6, means);
    gate_softmax<<<1, 384, 0, stream>>>(means, gate_w, gbuf);
    make_inv<<<LLEN / 256, 256, 0, stream>>>(ridx, invb);
    // 9) combine + residual + LN2
    combine_ln2<<<M2, 64, 0, stream>>>(x, y6, gbuf, invb, n2g, n2b, x1, xn2);
    // 10) MixFFN
    gemm_nt<1><<<dim3(M2 / 32, FCH / 32), 256, 0, stream>>>(xn2, CCH, fc1_w, fc1_b, nullptr, t, FCH, M2, FCH, CCH);
    peconv_gelu<<<(M2 * FCH) / 256, 256, 0, stream>>>(t, pe_w, pe_b, t2);
    gemm_nt<3><<<dim3(M2 / 32, CCH / 32), 256, 0, stream>>>(t2, FCH, fc2_w, fc2_b, x1, out, CCH, M2, CCH, FCH);
}

// Round 2
// 333.774 us; speedup vs baseline: 2.5909x; 2.5909x over previous
//
#include <hip/hip_runtime.h>
#include <math.h>

#define LLEN 4096
#define CCH 128
#define DI 384
#define NST 4
#define SBN 6        // 3 directions x B=2
#define NB 2
#define FCH 512
#define NCHUNK 64
#define TSTEP 64

typedef short bf16x8 __attribute__((ext_vector_type(8)));
typedef float f32x4 __attribute__((ext_vector_type(4)));

__device__ __forceinline__ float wave_sum(float v) {
#pragma unroll
    for (int o = 32; o > 0; o >>= 1) v += __shfl_xor(v, o);
    return v;
}

__device__ __forceinline__ short f2bf(float f) {
    unsigned int u = __float_as_uint(f);
    unsigned int r = (u + 0x7fffu + ((u >> 16) & 1u)) >> 16;
    return (short)r;
}

// ---------------- weight f32 -> bf16 (all six matrices, one kernel) ----------------
#define OFF_IN  0
#define OFF_XP  98304
#define OFF_DT  150528
#define OFF_OUT 199680
#define OFF_FC1 248832
#define OFF_FC2 314368
#define OFF_END 379904
__global__ __launch_bounds__(256) void convert_weights(const float* __restrict__ in_w,
                                                       const float* __restrict__ xp_w,
                                                       const float* __restrict__ dt_w,
                                                       const float* __restrict__ out_w,
                                                       const float* __restrict__ fc1_w,
                                                       const float* __restrict__ fc2_w,
                                                       short* __restrict__ wb)
{
    int i = blockIdx.x * 256 + threadIdx.x;
    float v;
    if (i < OFF_XP) v = in_w[i];
    else if (i < OFF_DT)  v = xp_w[i - OFF_XP];
    else if (i < OFF_OUT) v = dt_w[i - OFF_DT];
    else if (i < OFF_FC1) v = out_w[i - OFF_OUT];
    else if (i < OFF_FC2) v = fc1_w[i - OFF_FC1];
    else if (i < OFF_END) v = fc2_w[i - OFF_FC2];
    else return;
    wb[i] = f2bf(v);
}

// ---------------- LayerNorm over C=128, building x_in on the fly, bf16 out ----------------
__global__ __launch_bounds__(64) void prep_ln1(const float* __restrict__ x,
                                               const int* __restrict__ ridx,
                                               const float* __restrict__ g,
                                               const float* __restrict__ b,
                                               short* __restrict__ xn)
{
    int r = blockIdx.x;
    int sb = r / LLEN, l = r % LLEN;
    int s = sb >> 1, bb = sb & 1;
    int srcl = (s == 0) ? l : (s == 1 ? (LLEN - 1 - l) : ridx[l]);
    const float* src = x + ((size_t)bb * LLEN + srcl) * CCH;
    int lane = threadIdx.x;
    float v0 = src[lane], v1 = src[lane + 64];
    float m = wave_sum(v0 + v1) * (1.f / 128.f);
    float d0 = v0 - m, d1 = v1 - m;
    float var = wave_sum(d0 * d0 + d1 * d1) * (1.f / 128.f);
    float rstd = rsqrtf(var + 1e-5f);
    short* dst = xn + (size_t)r * CCH;
    dst[lane]      = f2bf(d0 * rstd * g[lane]      + b[lane]);
    dst[lane + 64] = f2bf(d1 * rstd * g[lane + 64] + b[lane + 64]);
}

// ---------------- MFMA bf16 GEMM: C[M,N] = act(A[M,K] @ W[N,K]^T + bias) ----------------
// EPI: 0=none 1=bias 2=bias+softplus 3=bias+residual 4=xp-split(bf16 cols0-127, f32 cols128-135)
template<int EPI>
__global__ __launch_bounds__(256) void gemm_mfma(const short* __restrict__ A, int lda,
                                                 const short* __restrict__ W, int ldw, int N,
                                                 const float* __restrict__ bias,
                                                 const float* __restrict__ res, int ldr,
                                                 float* __restrict__ C0, int ldc,
                                                 short* __restrict__ Cb,
                                                 float* __restrict__ C1,
                                                 int M, int Kd)
{
    __shared__ short Als[64 * 72];
    __shared__ short Wls[64 * 72];
    int tid = threadIdx.x;
    int wid = tid >> 6, lane = tid & 63;
    int wm = wid >> 1, wn = wid & 1;
    int l15 = lane & 15, l4 = lane >> 4;
    int bm = blockIdx.x * 64, bn = blockIdx.y * 64;
    int srow = tid >> 3, scol = (tid & 7) * 8;
    f32x4 acc[2][2] = {};
    for (int k0 = 0; k0 < Kd; k0 += 64) {
        bf16x8 av0 = *(const bf16x8*)&A[(size_t)(bm + srow) * lda + k0 + scol];
        bf16x8 av1 = *(const bf16x8*)&A[(size_t)(bm + srow + 32) * lda + k0 + scol];
        int n0 = bn + srow, n1 = bn + srow + 32;
        bf16x8 wv0 = {}; bf16x8 wv1 = {};
        if (n0 < N) wv0 = *(const bf16x8*)&W[(size_t)n0 * ldw + k0 + scol];
        if (n1 < N) wv1 = *(const bf16x8*)&W[(size_t)n1 * ldw + k0 + scol];
        __syncthreads();
        *(bf16x8*)&Als[srow * 72 + scol] = av0;
        *(bf16x8*)&Als[(srow + 32) * 72 + scol] = av1;
        *(bf16x8*)&Wls[srow * 72 + scol] = wv0;
        *(bf16x8*)&Wls[(srow + 32) * 72 + scol] = wv1;
        __syncthreads();
#pragma unroll
        for (int ks = 0; ks < 2; ks++) {
            bf16x8 af[2], bw[2];
#pragma unroll
            for (int f = 0; f < 2; f++) {
                af[f] = *(const bf16x8*)&Als[(wm * 32 + f * 16 + l15) * 72 + ks * 32 + l4 * 8];
                bw[f] = *(const bf16x8*)&Wls[(wn * 32 + f * 16 + l15) * 72 + ks * 32 + l4 * 8];
            }
#pragma unroll
            for (int i = 0; i < 2; i++)
#pragma unroll
                for (int j = 0; j < 2; j++)
                    acc[i][j] = __builtin_amdgcn_mfma_f32_16x16x32_bf16(af[i], bw[j], acc[i][j], 0, 0, 0);
        }
    }
#pragma unroll
    for (int i = 0; i < 2; i++) {
        int row0 = bm + wm * 32 + i * 16 + l4 * 4;
#pragma unroll
        for (int j = 0; j < 2; j++) {
            int col = bn + wn * 32 + j * 16 + l15;
            if (EPI == 4) {
                if (col < 128) {
#pragma unroll
                    for (int r = 0; r < 4; r++) Cb[(size_t)(row0 + r) * 128 + col] = f2bf(acc[i][j][r]);
                } else if (col < 136) {
#pragma unroll
                    for (int r = 0; r < 4; r++) C1[(size_t)(row0 + r) * 8 + (col - 128)] = acc[i][j][r];
                }
            } else if (col < N) {
                float bv = (EPI == 1 || EPI == 2 || EPI == 3) ? bias[col] : 0.f;
#pragma unroll
                for (int r = 0; r < 4; r++) {
                    float v = acc[i][j][r] + bv;
                    if (EPI == 2) v = (v > 20.f) ? v : log1pf(expf(v));
                    if (EPI == 3) v += res[(size_t)(row0 + r) * ldr + col];
                    C0[(size_t)(row0 + r) * ldc + col] = v;
                }
            }
        }
    }
}

// ---------------- depthwise causal conv K=4 + bias + SiLU (f32 + bf16 out) ----------------
__global__ __launch_bounds__(256) void dwconv_silu(const float* __restrict__ h,
                                                   const float* __restrict__ cw,
                                                   const float* __restrict__ cb,
                                                   float* __restrict__ u,
                                                   short* __restrict__ ub)
{
    int gid = blockIdx.x * 256 + threadIdx.x;
    int d = gid % DI;
    int row = gid / DI;
    int l = row % LLEN;
    float acc = cb[d];
#pragma unroll
    for (int k = 0; k < 4; k++) {
        int ls = l - 3 + k;
        if (ls >= 0) acc += cw[d * 4 + k] * h[(size_t)(row - l + ls) * DI + d];
    }
    float r = acc / (1.f + expf(-acc));
    u[(size_t)row * DI + d] = r;
    ub[(size_t)row * DI + d] = f2bf(r);
}

// ---------------- chunked selective scan ----------------
__global__ __launch_bounds__(DI) void scan_phaseA(const float* __restrict__ dt,
                                                  const float* __restrict__ bc,
                                                  const float* __restrict__ u,
                                                  const float* __restrict__ A_log,
                                                  float* __restrict__ P, float* __restrict__ S)
{
    int d = threadIdx.x;
    int chunk = blockIdx.x, sb = blockIdx.y;
    float a[NST];
#pragma unroll
    for (int n = 0; n < NST; n++) a[n] = -expf(A_log[d * NST + n]);
    float s[NST] = {0.f, 0.f, 0.f, 0.f}, p[NST] = {1.f, 1.f, 1.f, 1.f};
    int base = sb * LLEN + chunk * TSTEP;
    for (int t = 0; t < TSTEP; t++) {
        int row = base + t;
        float dtv = dt[(size_t)row * DI + d];
        float uv = u[(size_t)row * DI + d];
        float dtu = dtv * uv;
#pragma unroll
        for (int n = 0; n < NST; n++) {
            float dA = expf(dtv * a[n]);
            float Bv = bc[(size_t)row * 8 + n];
            s[n] = dA * s[n] + dtu * Bv;
            p[n] *= dA;
        }
    }
    int idx = ((sb * NCHUNK + chunk) * DI + d) * NST;
#pragma unroll
    for (int n = 0; n < NST; n++) { P[idx + n] = p[n]; S[idx + n] = s[n]; }
}

__global__ __launch_bounds__(256) void scan_phaseB(const float* __restrict__ P,
                                                   const float* __restrict__ S,
                                                   float* __restrict__ I)
{
    int gid = blockIdx.x * 256 + threadIdx.x;
    if (gid >= SBN * DI * NST) return;
    int dn = gid % (DI * NST);
    int sb = gid / (DI * NST);
    float st = 0.f;
    for (int c = 0; c < NCHUNK; c++) {
        int idx = (sb * NCHUNK + c) * DI * NST + dn;
        I[idx] = st;
        st = P[idx] * st + S[idx];
    }
}

__global__ __launch_bounds__(DI) void scan_phaseC(const float* __restrict__ dt,
                                                  const float* __restrict__ bc,
                                                  const float* __restrict__ u,
                                                  const float* __restrict__ A_log,
                                                  const float* __restrict__ Dp,
                                                  const float* __restrict__ gate,
                                                  const float* __restrict__ I,
                                                  short* __restrict__ ymix)
{
    int d = threadIdx.x;
    int chunk = blockIdx.x, sb = blockIdx.y;
    float a[NST];
#pragma unroll
    for (int n = 0; n < NST; n++) a[n] = -expf(A_log[d * NST + n]);
    int idx = ((sb * NCHUNK + chunk) * DI + d) * NST;
    float s[NST];
#pragma unroll
    for (int n = 0; n < NST; n++) s[n] = I[idx + n];
    float Dv = Dp[d];
    int base = sb * LLEN + chunk * TSTEP;
    for (int t = 0; t < TSTEP; t++) {
        int row = base + t;
        float dtv = dt[(size_t)row * DI + d];
        float uv = u[(size_t)row * DI + d];
        float dtu = dtv * uv;
        float y = 0.f;
#pragma unroll
        for (int n = 0; n < NST; n++) {
            float dA = expf(dtv * a[n]);
            float Bv = bc[(size_t)row * 8 + n];
            float Cv = bc[(size_t)row * 8 + 4 + n];
            s[n] = dA * s[n] + dtu * Bv;
            y += s[n] * Cv;
        }
        float gt = gate[(size_t)row * DI + d];
        float sg = gt / (1.f + expf(-gt));
        ymix[(size_t)row * DI + d] = f2bf((y + uv * Dv) * sg);
    }
}

// ---------------- column means of y6 per (sb) ----------------
__global__ __launch_bounds__(256) void colmeans(const float* __restrict__ y6, float* __restrict__ means)
{
    int sb = blockIdx.x, rc = blockIdx.y;
    int c = threadIdx.x & 127, r0 = threadIdx.x >> 7;
    float ssum = 0.f;
    for (int r = rc * 256 + r0; r < rc * 256 + 256; r += 2)
        ssum += y6[((size_t)sb * LLEN + r) * CCH + c];
    __shared__ float red[128];
    if (r0) red[c] = ssum;
    __syncthreads();
    if (!r0) atomicAdd(&means[sb * CCH + c], ssum + red[c]);
}

__global__ __launch_bounds__(384) void gate_softmax(const float* __restrict__ means,
                                                    const float* __restrict__ gw,
                                                    float* __restrict__ g)
{
    int lane = threadIdx.x & 63, p = threadIdx.x >> 6;
    int bb = p / 3, j = p % 3;
    float part = 0.f;
    for (int i = lane; i < 384; i += 64) {
        int s = i >> 7, c = i & 127;
        part += means[(s * 2 + bb) * 128 + c] * (1.f / 4096.f) * gw[j * 384 + i];
    }
    part = wave_sum(part);
    __shared__ float lg[6];
    if (lane == 0) lg[p] = part;
    __syncthreads();
    if (threadIdx.x < 2) {
        int b2 = threadIdx.x;
        float a0 = lg[b2 * 3], a1 = lg[b2 * 3 + 1], a2 = lg[b2 * 3 + 2];
        float mx = fmaxf(a0, fmaxf(a1, a2));
        float e0 = expf(a0 - mx), e1 = expf(a1 - mx), e2 = expf(a2 - mx);
        float inv = 1.f / (e0 + e1 + e2);
        g[b2 * 3] = e0 * inv; g[b2 * 3 + 1] = e1 * inv; g[b2 * 3 + 2] = e2 * inv;
    }
}

__global__ void make_inv(const int* __restrict__ ridx, int* __restrict__ inv)
{
    int l = blockIdx.x * blockDim.x + threadIdx.x;
    if (l < LLEN) inv[ridx[l]] = l;
}

// combine 3 directions + residual + LayerNorm2 (x1 f32, xn2 bf16)
__global__ __launch_bounds__(64) void combine_ln2(const float* __restrict__ x,
                                                  const float* __restrict__ y6,
                                                  const float* __restrict__ g,
                                                  const int* __restrict__ inv,
                                                  const float* __restrict__ n2g,
                                                  const float* __restrict__ n2b,
                                                  float* __restrict__ x1,
                                                  short* __restrict__ xn2)
{
    int r = blockIdx.x;
    int bb = r / LLEN, l = r % LLEN;
    int lane = threadIdx.x;
    float g0 = g[bb * 3 + 0], g1 = g[bb * 3 + 1], g2 = g[bb * 3 + 2];
    int il = inv[l];
    size_t fo = ((size_t)(0 + bb) * LLEN + l) * CCH;
    size_t ro = ((size_t)(2 + bb) * LLEN + (LLEN - 1 - l)) * CCH;
    size_t so = ((size_t)(4 + bb) * LLEN + il) * CCH;
    size_t xo = ((size_t)bb * LLEN + l) * CCH;
    float v0 = x[xo + lane]      + g0 * y6[fo + lane]      + g1 * y6[ro + lane]      + g2 * y6[so + lane];
    float v1 = x[xo + lane + 64] + g0 * y6[fo + lane + 64] + g1 * y6[ro + lane + 64] + g2 * y6[so + lane + 64];
    float m = wave_sum(v0 + v1) * (1.f / 128.f);
    float d0 = v0 - m, d1 = v1 - m;
    float var = wave_sum(d0 * d0 + d1 * d1) * (1.f / 128.f);
    float rstd = rsqrtf(var + 1e-5f);
    x1[xo + lane] = v0; x1[xo + lane + 64] = v1;
    xn2[xo + lane]      = f2bf(d0 * rstd * n2g[lane]      + n2b[lane]);
    xn2[xo + lane + 64] = f2bf(d1 * rstd * n2g[lane + 64] + n2b[lane + 64]);
}

// ---------------- 3x3 depthwise conv + exact GeLU (bf16 out) ----------------
__global__ __launch_bounds__(256) void peconv_gelu(const float* __restrict__ t,
                                                   const float* __restrict__ pw,
                                                   const float* __restrict__ pb,
                                                   short* __restrict__ t2)
{
    int gid = blockIdx.x * 256 + threadIdx.x;
    int f = gid & (FCH - 1);
    int pix = gid >> 9;
    int bb = pix >> 12;
    int l = pix & 4095;
    int h = l >> 6, w = l & 63;
    float acc = pb[f];
#pragma unroll
    for (int dy = -1; dy <= 1; dy++) {
        int hh = h + dy;
        if (hh < 0 || hh > 63) continue;
#pragma unroll
        for (int dx = -1; dx <= 1; dx++) {
            int ww = w + dx;
            if (ww < 0 || ww > 63) continue;
            acc += pw[f * 9 + (dy + 1) * 3 + (dx + 1)] * t[((size_t)(bb * 4096 + hh * 64 + ww)) * FCH + f];
        }
    }
    t2[(size_t)pix * FCH + f] = f2bf(0.5f * acc * (1.f + erff(acc * 0.70710678118654752f)));
}

extern "C" void kernel_launch(void* const* d_in, const int* in_sizes, int n_in,
                              void* d_out, int out_size, void* d_ws, size_t ws_size,
                              hipStream_t stream)
{
    (void)in_sizes; (void)n_in; (void)ws_size; (void)out_size;
    const float* x      = (const float*)d_in[0];
    const int*   ridx   = (const int*)d_in[1];
    const float* n1g    = (const float*)d_in[4];
    const float* n1b    = (const float*)d_in[5];
    const float* in_w   = (const float*)d_in[6];
    const float* conv_w = (const float*)d_in[7];
    const float* conv_b = (const float*)d_in[8];
    const float* xp_w   = (const float*)d_in[9];
    const float* dt_w   = (const float*)d_in[10];
    const float* dt_b   = (const float*)d_in[11];
    const float* A_log  = (const float*)d_in[12];
    const float* Dp     = (const float*)d_in[13];
    const float* out_w  = (const float*)d_in[14];
    const float* n2g    = (const float*)d_in[15];
    const float* n2b    = (const float*)d_in[16];
    const float* gate_w = (const float*)d_in[17];
    const float* fc1_w  = (const float*)d_in[18];
    const float* fc1_b  = (const float*)d_in[19];
    const float* pe_w   = (const float*)d_in[20];
    const float* pe_b   = (const float*)d_in[21];
    const float* fc2_w  = (const float*)d_in[22];
    const float* fc2_b  = (const float*)d_in[23];
    float* out = (float*)d_out;

    const size_t SZ_HD = (size_t)SBN * LLEN * DI;          // 9,437,184
    float* ws   = (float*)d_ws;
    float* bufA = ws;                                      // h -> dt -> t(fc1 out)
    float* bufB = bufA + SZ_HD;                            // gate -> x1 + xn2(bf16)
    float* bufC = bufB + SZ_HD;                            // u_f32 -> y6
    short* bufD = (short*)(bufC + SZ_HD);                  // u_bf16 -> ymix -> t2   (9,437,184 bf16)
    float* bufF = (float*)(bufD + SZ_HD);                  // xn(bf16) -> xp_dt(bf16) -> P/S/I (1,769,472 f)
    float* xpbc = bufF + 1769472;                          // 196,608 f
    short* wb   = (short*)(xpbc + 196608);                 // 379,904 bf16
    float* means = (float*)(wb + OFF_END);
    float* gbuf  = means + 768;
    int*   invb  = (int*)(gbuf + 8);

    short* xn    = (short*)bufF;
    short* xp_dt = (short*)bufF;
    float* P = bufF, *S = bufF + 589824, *I = bufF + 1179648;
    float* hbuf = bufA, *dtb = bufA, *tbuf = bufA;
    float* gate = bufB, *x1 = bufB;
    short* xn2  = (short*)(bufB + 2097152);
    float* u    = bufC, *y6 = bufC;
    short* ub   = bufD, *ymix = bufD, *t2 = bufD;

    const int M6 = SBN * LLEN;   // 24576
    const int M2 = NB * LLEN;    // 8192

    convert_weights<<<(OFF_END + 255) / 256, 256, 0, stream>>>(in_w, xp_w, dt_w, out_w, fc1_w, fc2_w, wb);
    prep_ln1<<<M6, 64, 0, stream>>>(x, ridx, n1g, n1b, xn);
    // in_proj (h, gate)
    gemm_mfma<0><<<dim3(M6 / 64, 6), 256, 0, stream>>>(xn, CCH, wb + OFF_IN, CCH, DI, nullptr, nullptr, 0, hbuf, DI, nullptr, nullptr, M6, CCH);
    gemm_mfma<0><<<dim3(M6 / 64, 6), 256, 0, stream>>>(xn, CCH, wb + OFF_IN + DI * CCH, CCH, DI, nullptr, nullptr, 0, gate, DI, nullptr, nullptr, M6, CCH);
    dwconv_silu<<<(M6 * DI) / 256, 256, 0, stream>>>(hbuf, conv_w, conv_b, u, ub);
    // x_proj: bf16 dt-part + f32 B/C part
    gemm_mfma<4><<<dim3(M6 / 64, 3), 256, 0, stream>>>(ub, DI, wb + OFF_XP, DI, 136, nullptr, nullptr, 0, nullptr, 0, xp_dt, xpbc, M6, DI);
    // dt_proj + softplus
    gemm_mfma<2><<<dim3(M6 / 64, 6), 256, 0, stream>>>(xp_dt, CCH, wb + OFF_DT, CCH, DI, dt_b, nullptr, 0, dtb, DI, nullptr, nullptr, M6, CCH);
    // selective scan
    scan_phaseA<<<dim3(NCHUNK, SBN), DI, 0, stream>>>(dtb, xpbc, u, A_log, P, S);
    scan_phaseB<<<(SBN * DI * NST + 255) / 256, 256, 0, stream>>>(P, S, I);
    scan_phaseC<<<dim3(NCHUNK, SBN), DI, 0, stream>>>(dtb, xpbc, u, A_log, Dp, gate, I, ymix);
    // out_proj
    gemm_mfma<0><<<dim3(M6 / 64, 2), 256, 0, stream>>>(ymix, DI, wb + OFF_OUT, DI, CCH, nullptr, nullptr, 0, y6, CCH, nullptr, nullptr, M6, DI);
    // direction gating
    hipMemsetAsync(means, 0, 768 * sizeof(float), stream);
    colmeans<<<dim3(SBN, 16), 256, 0, stream>>>(y6, means);
    gate_softmax<<<1, 384, 0, stream>>>(means, gate_w, gbuf);
    make_inv<<<LLEN / 256, 256, 0, stream>>>(ridx, invb);
    combine_ln2<<<M2, 64, 0, stream>>>(x, y6, gbuf, invb, n2g, n2b, x1, xn2);
    // MixFFN
    gemm_mfma<1><<<dim3(M2 / 64, 8), 256, 0, stream>>>(xn2, CCH, wb + OFF_FC1, CCH, FCH, fc1_b, nullptr, 0, tbuf, FCH, nullptr, nullptr, M2, CCH);
    peconv_gelu<<<(M2 * FCH) / 256, 256, 0, stream>>>(tbuf, pe_w, pe_b, t2);
    gemm_mfma<3><<<dim3(M2 / 64, 2), 256, 0, stream>>>(t2, FCH, wb + OFF_FC2, FCH, CCH, fc2_b, x1, CCH, out, CCH, nullptr, nullptr, M2, FCH);
}

// Round 3
// 263.240 us; speedup vs baseline: 3.2851x; 1.2679x over previous
//
#include <hip/hip_runtime.h>
#include <math.h>

#define LLEN 4096
#define CCH 128
#define DI 384
#define NST 4
#define SBN 6        // 3 directions x B=2
#define NB 2
#define FCH 512
#define NCHUNK 128
#define TSTEP 32

typedef short bf16x8 __attribute__((ext_vector_type(8)));
typedef float f32x4 __attribute__((ext_vector_type(4)));

__device__ __forceinline__ float wave_sum(float v) {
#pragma unroll
    for (int o = 32; o > 0; o >>= 1) v += __shfl_xor(v, o);
    return v;
}

__device__ __forceinline__ short f2bf(float f) {
    unsigned int u = __float_as_uint(f);
    unsigned int r = (u + 0x7fffu + ((u >> 16) & 1u)) >> 16;
    return (short)r;
}
__device__ __forceinline__ float bf2f(short s) {
    return __uint_as_float(((unsigned int)(unsigned short)s) << 16);
}

// ---------------- weight bf16 pool offsets (elements) ----------------
#define OFF_IN  0         // in_w            768x128
#define OFF_BC  98304     // xp_w rows 128..135   8x384
#define OFF_DTC 101376    // composed dt_w @ xp_w[:128]  384x384
#define OFF_OUT 248832    // out_w           128x384
#define OFF_FC1 297984    // fc1_w           512x128
#define OFF_FC2 363520    // fc2_w           128x512
#define OFF_END 429056

__global__ __launch_bounds__(256) void convert_weights(const float* __restrict__ in_w,
                                                       const float* __restrict__ xp_w,
                                                       const float* __restrict__ out_w,
                                                       const float* __restrict__ fc1_w,
                                                       const float* __restrict__ fc2_w,
                                                       short* __restrict__ wb)
{
    int i = blockIdx.x * 256 + threadIdx.x;
    float v;
    if (i < OFF_BC) v = in_w[i];
    else if (i < OFF_DTC) v = xp_w[128 * 384 + (i - OFF_BC)];
    else if (i < OFF_OUT) return;                      // composed region (compose_dtw writes it)
    else if (i < OFF_FC1) v = out_w[i - OFF_OUT];
    else if (i < OFF_FC2) v = fc1_w[i - OFF_FC1];
    else if (i < OFF_END) v = fc2_w[i - OFF_FC2];
    else return;
    wb[i] = f2bf(v);
}

// Wc[j,k] = sum_n dt_w[j,n] * xp_w[n,k]   (j,k in [0,384), n in [0,128))
__global__ __launch_bounds__(256) void compose_dtw(const float* __restrict__ dt_w,
                                                   const float* __restrict__ xp_w,
                                                   short* __restrict__ wc)
{
    int k = blockIdx.x * 16 + threadIdx.x;
    int j = blockIdx.y * 16 + threadIdx.y;
    float acc = 0.f;
#pragma unroll 8
    for (int n = 0; n < 128; n++)
        acc += dt_w[j * 128 + n] * xp_w[n * 384 + k];
    wc[j * 384 + k] = f2bf(acc);
}

// ---------------- LayerNorm over C=128, building x_in on the fly, bf16 out ----------------
__global__ __launch_bounds__(64) void prep_ln1(const float* __restrict__ x,
                                               const int* __restrict__ ridx,
                                               const float* __restrict__ g,
                                               const float* __restrict__ b,
                                               short* __restrict__ xn)
{
    int r = blockIdx.x;
    int sb = r / LLEN, l = r % LLEN;
    int s = sb >> 1, bb = sb & 1;
    int srcl = (s == 0) ? l : (s == 1 ? (LLEN - 1 - l) : ridx[l]);
    const float* src = x + ((size_t)bb * LLEN + srcl) * CCH;
    int lane = threadIdx.x;
    float v0 = src[lane], v1 = src[lane + 64];
    float m = wave_sum(v0 + v1) * (1.f / 128.f);
    float d0 = v0 - m, d1 = v1 - m;
    float var = wave_sum(d0 * d0 + d1 * d1) * (1.f / 128.f);
    float rstd = rsqrtf(var + 1e-5f);
    short* dst = xn + (size_t)r * CCH;
    dst[lane]      = f2bf(d0 * rstd * g[lane]      + b[lane]);
    dst[lane + 64] = f2bf(d1 * rstd * g[lane + 64] + b[lane + 64]);
}

// ---------------- MFMA bf16 GEMM: C[M,N] = act(A[M,K] @ W[N,K]^T + bias) ----------------
// EPI: 0=f32  1=bias f32  2=bias+softplus bf16  3=bias+residual f32  5=bf16  6=bias bf16
template<int EPI>
__global__ __launch_bounds__(256) void gemm_mfma(const short* __restrict__ A, int lda,
                                                 const short* __restrict__ W, int ldw, int N,
                                                 const float* __restrict__ bias,
                                                 const float* __restrict__ res, int ldr,
                                                 float* __restrict__ C0,
                                                 short* __restrict__ Cb, int ldc,
                                                 int M, int Kd)
{
    __shared__ short Als[64 * 72];
    __shared__ short Wls[64 * 72];
    int tid = threadIdx.x;
    int wid = tid >> 6, lane = tid & 63;
    int wm = wid >> 1, wn = wid & 1;
    int l15 = lane & 15, l4 = lane >> 4;
    int bm = blockIdx.x * 64, bn = blockIdx.y * 64;
    int srow = tid >> 3, scol = (tid & 7) * 8;
    f32x4 acc[2][2] = {};
    for (int k0 = 0; k0 < Kd; k0 += 64) {
        bf16x8 av0 = *(const bf16x8*)&A[(size_t)(bm + srow) * lda + k0 + scol];
        bf16x8 av1 = *(const bf16x8*)&A[(size_t)(bm + srow + 32) * lda + k0 + scol];
        int n0 = bn + srow, n1 = bn + srow + 32;
        bf16x8 wv0 = {}; bf16x8 wv1 = {};
        if (n0 < N) wv0 = *(const bf16x8*)&W[(size_t)n0 * ldw + k0 + scol];
        if (n1 < N) wv1 = *(const bf16x8*)&W[(size_t)n1 * ldw + k0 + scol];
        __syncthreads();
        *(bf16x8*)&Als[srow * 72 + scol] = av0;
        *(bf16x8*)&Als[(srow + 32) * 72 + scol] = av1;
        *(bf16x8*)&Wls[srow * 72 + scol] = wv0;
        *(bf16x8*)&Wls[(srow + 32) * 72 + scol] = wv1;
        __syncthreads();
#pragma unroll
        for (int ks = 0; ks < 2; ks++) {
            bf16x8 af[2], bw[2];
#pragma unroll
            for (int f = 0; f < 2; f++) {
                af[f] = *(const bf16x8*)&Als[(wm * 32 + f * 16 + l15) * 72 + ks * 32 + l4 * 8];
                bw[f] = *(const bf16x8*)&Wls[(wn * 32 + f * 16 + l15) * 72 + ks * 32 + l4 * 8];
            }
#pragma unroll
            for (int i = 0; i < 2; i++)
#pragma unroll
                for (int j = 0; j < 2; j++)
                    acc[i][j] = __builtin_amdgcn_mfma_f32_16x16x32_bf16(af[i], bw[j], acc[i][j], 0, 0, 0);
        }
    }
#pragma unroll
    for (int i = 0; i < 2; i++) {
        int row0 = bm + wm * 32 + i * 16 + l4 * 4;
#pragma unroll
        for (int j = 0; j < 2; j++) {
            int col = bn + wn * 32 + j * 16 + l15;
            if (col < N) {
                float bv = (EPI == 1 || EPI == 2 || EPI == 3 || EPI == 6) ? bias[col] : 0.f;
#pragma unroll
                for (int r = 0; r < 4; r++) {
                    float v = acc[i][j][r] + bv;
                    if (EPI == 2) v = (v > 20.f) ? v : __logf(1.f + __expf(v));
                    if (EPI == 3) v += res[(size_t)(row0 + r) * ldr + col];
                    if (EPI == 2 || EPI == 5 || EPI == 6)
                        Cb[(size_t)(row0 + r) * ldc + col] = f2bf(v);
                    else
                        C0[(size_t)(row0 + r) * ldc + col] = v;
                }
            }
        }
    }
}

// ---------------- depthwise causal conv K=4 + bias + SiLU (bf16 in/out) ----------------
__global__ __launch_bounds__(256) void dwconv_silu(const short* __restrict__ hg,
                                                   const float* __restrict__ cw,
                                                   const float* __restrict__ cb,
                                                   short* __restrict__ ub)
{
    int gid = blockIdx.x * 256 + threadIdx.x;
    int d = gid % DI;
    int row = gid / DI;
    int l = row % LLEN;
    float acc = cb[d];
#pragma unroll
    for (int k = 0; k < 4; k++) {
        int ls = l - 3 + k;
        if (ls >= 0) acc += cw[d * 4 + k] * bf2f(hg[(size_t)(row - l + ls) * 768 + d]);
    }
    float r = acc * __builtin_amdgcn_rcpf(1.f + __expf(-acc));
    ub[(size_t)row * DI + d] = f2bf(r);
}

// ---------------- chunked selective scan ----------------
__global__ __launch_bounds__(DI) void scan_phaseA(const short* __restrict__ dt,
                                                  const float* __restrict__ bc,
                                                  const short* __restrict__ u,
                                                  const float* __restrict__ A_log,
                                                  float* __restrict__ P, float* __restrict__ S)
{
    int d = threadIdx.x;
    int chunk = blockIdx.x, sb = blockIdx.y;
    float a[NST];
#pragma unroll
    for (int n = 0; n < NST; n++) a[n] = -__expf(A_log[d * NST + n]);
    float s[NST] = {0.f, 0.f, 0.f, 0.f}, p[NST] = {1.f, 1.f, 1.f, 1.f};
    int base = sb * LLEN + chunk * TSTEP;
    for (int t = 0; t < TSTEP; t++) {
        int row = base + t;
        float dtv = bf2f(dt[(size_t)row * DI + d]);
        float uv = bf2f(u[(size_t)row * DI + d]);
        float dtu = dtv * uv;
#pragma unroll
        for (int n = 0; n < NST; n++) {
            float dA = __expf(dtv * a[n]);
            float Bv = bc[(size_t)row * 8 + n];
            s[n] = dA * s[n] + dtu * Bv;
            p[n] *= dA;
        }
    }
    int idx = ((sb * NCHUNK + chunk) * DI + d) * NST;
#pragma unroll
    for (int n = 0; n < NST; n++) { P[idx + n] = p[n]; S[idx + n] = s[n]; }
}

__global__ __launch_bounds__(256) void scan_phaseB(const float* __restrict__ P,
                                                   const float* __restrict__ S,
                                                   float* __restrict__ I)
{
    int gid = blockIdx.x * 256 + threadIdx.x;
    if (gid >= SBN * DI * NST) return;
    int dn = gid % (DI * NST);
    int sb = gid / (DI * NST);
    float st = 0.f;
#pragma unroll 4
    for (int c = 0; c < NCHUNK; c++) {
        int idx = (sb * NCHUNK + c) * DI * NST + dn;
        I[idx] = st;
        st = P[idx] * st + S[idx];
    }
}

__global__ __launch_bounds__(DI) void scan_phaseC(const short* __restrict__ dt,
                                                  const float* __restrict__ bc,
                                                  const short* __restrict__ u,
                                                  const float* __restrict__ A_log,
                                                  const float* __restrict__ Dp,
                                                  const short* __restrict__ hg,
                                                  const float* __restrict__ I,
                                                  short* __restrict__ ymix)
{
    int d = threadIdx.x;
    int chunk = blockIdx.x, sb = blockIdx.y;
    float a[NST];
#pragma unroll
    for (int n = 0; n < NST; n++) a[n] = -__expf(A_log[d * NST + n]);
    int idx = ((sb * NCHUNK + chunk) * DI + d) * NST;
    float s[NST];
#pragma unroll
    for (int n = 0; n < NST; n++) s[n] = I[idx + n];
    float Dv = Dp[d];
    int base = sb * LLEN + chunk * TSTEP;
    for (int t = 0; t < TSTEP; t++) {
        int row = base + t;
        float dtv = bf2f(dt[(size_t)row * DI + d]);
        float uv = bf2f(u[(size_t)row * DI + d]);
        float dtu = dtv * uv;
        float y = 0.f;
#pragma unroll
        for (int n = 0; n < NST; n++) {
            float dA = __expf(dtv * a[n]);
            float Bv = bc[(size_t)row * 8 + n];
            float Cv = bc[(size_t)row * 8 + 4 + n];
            s[n] = dA * s[n] + dtu * Bv;
            y += s[n] * Cv;
        }
        float gt = bf2f(hg[(size_t)row * 768 + 384 + d]);
        float sg = gt * __builtin_amdgcn_rcpf(1.f + __expf(-gt));
        ymix[(size_t)row * DI + d] = f2bf((y + uv * Dv) * sg);
    }
}

// ---------------- column means of y6 per (sb) ----------------
__global__ __launch_bounds__(256) void colmeans(const float* __restrict__ y6, float* __restrict__ means)
{
    int sb = blockIdx.x, rc = blockIdx.y;
    int c = threadIdx.x & 127, r0 = threadIdx.x >> 7;
    float ssum = 0.f;
    for (int r = rc * 256 + r0; r < rc * 256 + 256; r += 2)
        ssum += y6[((size_t)sb * LLEN + r) * CCH + c];
    __shared__ float red[128];
    if (r0) red[c] = ssum;
    __syncthreads();
    if (!r0) atomicAdd(&means[sb * CCH + c], ssum + red[c]);
}

__global__ __launch_bounds__(384) void gate_softmax(const float* __restrict__ means,
                                                    const float* __restrict__ gw,
                                                    float* __restrict__ g)
{
    int lane = threadIdx.x & 63, p = threadIdx.x >> 6;
    int bb = p / 3, j = p % 3;
    float part = 0.f;
    for (int i = lane; i < 384; i += 64) {
        int s = i >> 7, c = i & 127;
        part += means[(s * 2 + bb) * 128 + c] * (1.f / 4096.f) * gw[j * 384 + i];
    }
    part = wave_sum(part);
    __shared__ float lg[6];
    if (lane == 0) lg[p] = part;
    __syncthreads();
    if (threadIdx.x < 2) {
        int b2 = threadIdx.x;
        float a0 = lg[b2 * 3], a1 = lg[b2 * 3 + 1], a2 = lg[b2 * 3 + 2];
        float mx = fmaxf(a0, fmaxf(a1, a2));
        float e0 = __expf(a0 - mx), e1 = __expf(a1 - mx), e2 = __expf(a2 - mx);
        float inv = __builtin_amdgcn_rcpf(e0 + e1 + e2);
        g[b2 * 3] = e0 * inv; g[b2 * 3 + 1] = e1 * inv; g[b2 * 3 + 2] = e2 * inv;
    }
}

__global__ void make_inv(const int* __restrict__ ridx, int* __restrict__ inv)
{
    int l = blockIdx.x * blockDim.x + threadIdx.x;
    if (l < LLEN) inv[ridx[l]] = l;
}

// combine 3 directions + residual + LayerNorm2 (x1 f32, xn2 bf16)
__global__ __launch_bounds__(64) void combine_ln2(const float* __restrict__ x,
                                                  const float* __restrict__ y6,
                                                  const float* __restrict__ g,
                                                  const int* __restrict__ inv,
                                                  const float* __restrict__ n2g,
                                                  const float* __restrict__ n2b,
                                                  float* __restrict__ x1,
                                                  short* __restrict__ xn2)
{
    int r = blockIdx.x;
    int bb = r / LLEN, l = r % LLEN;
    int lane = threadIdx.x;
    float g0 = g[bb * 3 + 0], g1 = g[bb * 3 + 1], g2 = g[bb * 3 + 2];
    int il = inv[l];
    size_t fo = ((size_t)(0 + bb) * LLEN + l) * CCH;
    size_t ro = ((size_t)(2 + bb) * LLEN + (LLEN - 1 - l)) * CCH;
    size_t so = ((size_t)(4 + bb) * LLEN + il) * CCH;
    size_t xo = ((size_t)bb * LLEN + l) * CCH;
    float v0 = x[xo + lane]      + g0 * y6[fo + lane]      + g1 * y6[ro + lane]      + g2 * y6[so + lane];
    float v1 = x[xo + lane + 64] + g0 * y6[fo + lane + 64] + g1 * y6[ro + lane + 64] + g2 * y6[so + lane + 64];
    float m = wave_sum(v0 + v1) * (1.f / 128.f);
    float d0 = v0 - m, d1 = v1 - m;
    float var = wave_sum(d0 * d0 + d1 * d1) * (1.f / 128.f);
    float rstd = rsqrtf(var + 1e-5f);
    x1[xo + lane] = v0; x1[xo + lane + 64] = v1;
    xn2[xo + lane]      = f2bf(d0 * rstd * n2g[lane]      + n2b[lane]);
    xn2[xo + lane + 64] = f2bf(d1 * rstd * n2g[lane + 64] + n2b[lane + 64]);
}

// ---------------- 3x3 depthwise conv + exact GeLU (bf16 in/out) ----------------
__global__ __launch_bounds__(256) void peconv_gelu(const short* __restrict__ t,
                                                   const float* __restrict__ pw,
                                                   const float* __restrict__ pb,
                                                   short* __restrict__ t2)
{
    int gid = blockIdx.x * 256 + threadIdx.x;
    int f = gid & (FCH - 1);
    int pix = gid >> 9;
    int bb = pix >> 12;
    int l = pix & 4095;
    int h = l >> 6, w = l & 63;
    float acc = pb[f];
#pragma unroll
    for (int dy = -1; dy <= 1; dy++) {
        int hh = h + dy;
        if (hh < 0 || hh > 63) continue;
#pragma unroll
        for (int dx = -1; dx <= 1; dx++) {
            int ww = w + dx;
            if (ww < 0 || ww > 63) continue;
            acc += pw[f * 9 + (dy + 1) * 3 + (dx + 1)] * bf2f(t[((size_t)(bb * 4096 + hh * 64 + ww)) * FCH + f]);
        }
    }
    t2[(size_t)pix * FCH + f] = f2bf(0.5f * acc * (1.f + erff(acc * 0.70710678118654752f)));
}

extern "C" void kernel_launch(void* const* d_in, const int* in_sizes, int n_in,
                              void* d_out, int out_size, void* d_ws, size_t ws_size,
                              hipStream_t stream)
{
    (void)in_sizes; (void)n_in; (void)ws_size; (void)out_size;
    const float* x      = (const float*)d_in[0];
    const int*   ridx   = (const int*)d_in[1];
    const float* n1g    = (const float*)d_in[4];
    const float* n1b    = (const float*)d_in[5];
    const float* in_w   = (const float*)d_in[6];
    const float* conv_w = (const float*)d_in[7];
    const float* conv_b = (const float*)d_in[8];
    const float* xp_w   = (const float*)d_in[9];
    const float* dt_w   = (const float*)d_in[10];
    const float* dt_b   = (const float*)d_in[11];
    const float* A_log  = (const float*)d_in[12];
    const float* Dp     = (const float*)d_in[13];
    const float* out_w  = (const float*)d_in[14];
    const float* n2g    = (const float*)d_in[15];
    const float* n2b    = (const float*)d_in[16];
    const float* gate_w = (const float*)d_in[17];
    const float* fc1_w  = (const float*)d_in[18];
    const float* fc1_b  = (const float*)d_in[19];
    const float* pe_w   = (const float*)d_in[20];
    const float* pe_b   = (const float*)d_in[21];
    const float* fc2_w  = (const float*)d_in[22];
    const float* fc2_b  = (const float*)d_in[23];
    float* out = (float*)d_out;

    float* ws = (float*)d_ws;
    short* wb   = (short*)ws;                       // 429,056 bf16 (215,040 f32 slots)
    float* regA = ws + 215040;                      // xn(bf16) -> P(f32) -> tbuf(bf16)   [2,097,152 f32]
    float* regB = regA + 2097152;                   // hg(bf16) -> {y6,x1,xn2,t2}         [9,437,184 f32]
    float* regC = regB + 9437184;                   // ub(bf16)                           [4,718,592 f32]
    float* regD = regC + 4718592;                   // ymix(bf16)                         [4,718,592 f32]
    float* regE = regD + 4718592;                   // dtb(bf16)                          [4,718,592 f32]
    float* regF = regE + 4718592;                   // S, I (f32)                         [2,359,296 f32]
    float* regG = regF + 2359296;                   // xpbc (f32)                         [196,608 f32]
    float* smallb = regG + 196608;

    short* xn   = (short*)regA;
    float* P    = regA;
    short* tbuf = (short*)regA;
    short* hg   = (short*)regB;
    float* y6   = regB;
    float* x1   = regB + 3145728;
    short* xn2  = (short*)(regB + 4194304);
    short* t2   = (short*)(regB + 4718592);
    short* ub   = (short*)regC;
    short* ymix = (short*)regD;
    short* dtb  = (short*)regE;
    float* S    = regF;
    float* I    = regF + 1179648;
    float* xpbc = regG;
    float* means = smallb;
    float* gbuf  = smallb + 768;
    int*   invb  = (int*)(gbuf + 8);

    const int M6 = SBN * LLEN;   // 24576
    const int M2 = NB * LLEN;    // 8192

    convert_weights<<<(OFF_END + 255) / 256, 256, 0, stream>>>(in_w, xp_w, out_w, fc1_w, fc2_w, wb);
    compose_dtw<<<dim3(24, 24), dim3(16, 16), 0, stream>>>(dt_w, xp_w, wb + OFF_DTC);
    prep_ln1<<<M6, 64, 0, stream>>>(x, ridx, n1g, n1b, xn);
    // fused in_proj: [h | gate] N=768, bf16 out
    gemm_mfma<5><<<dim3(M6 / 64, 12), 256, 0, stream>>>(xn, CCH, wb + OFF_IN, CCH, 768, nullptr, nullptr, 0, nullptr, hg, 768, M6, CCH);
    dwconv_silu<<<(M6 * DI) / 256, 256, 0, stream>>>(hg, conv_w, conv_b, ub);
    // B/C projection: N=8, f32 out
    gemm_mfma<0><<<dim3(M6 / 64, 1), 256, 0, stream>>>(ub, DI, wb + OFF_BC, DI, 8, nullptr, nullptr, 0, xpbc, nullptr, 8, M6, DI);
    // composed dt projection + softplus, bf16 out
    gemm_mfma<2><<<dim3(M6 / 64, 6), 256, 0, stream>>>(ub, DI, wb + OFF_DTC, DI, DI, dt_b, nullptr, 0, nullptr, dtb, DI, M6, DI);
    // selective scan
    scan_phaseA<<<dim3(NCHUNK, SBN), DI, 0, stream>>>(dtb, xpbc, ub, A_log, P, S);
    scan_phaseB<<<(SBN * DI * NST + 255) / 256, 256, 0, stream>>>(P, S, I);
    scan_phaseC<<<dim3(NCHUNK, SBN), DI, 0, stream>>>(dtb, xpbc, ub, A_log, Dp, hg, I, ymix);
    // out_proj
    gemm_mfma<0><<<dim3(M6 / 64, 2), 256, 0, stream>>>(ymix, DI, wb + OFF_OUT, DI, CCH, nullptr, nullptr, 0, y6, nullptr, CCH, M6, DI);
    // direction gating
    hipMemsetAsync(means, 0, 768 * sizeof(float), stream);
    colmeans<<<dim3(SBN, 16), 256, 0, stream>>>(y6, means);
    gate_softmax<<<1, 384, 0, stream>>>(means, gate_w, gbuf);
    make_inv<<<LLEN / 256, 256, 0, stream>>>(ridx, invb);
    combine_ln2<<<M2, 64, 0, stream>>>(x, y6, gbuf, invb, n2g, n2b, x1, xn2);
    // MixFFN
    gemm_mfma<6><<<dim3(M2 / 64, 8), 256, 0, stream>>>(xn2, CCH, wb + OFF_FC1, CCH, FCH, fc1_b, nullptr, 0, nullptr, tbuf, FCH, M2, CCH);
    peconv_gelu<<<(M2 * FCH) / 256, 256, 0, stream>>>(tbuf, pe_w, pe_b, t2);
    gemm_mfma<3><<<dim3(M2 / 64, 2), 256, 0, stream>>>(t2, FCH, wb + OFF_FC2, FCH, CCH, fc2_b, x1, CCH, out, nullptr, CCH, M2, FCH);
}

// Round 4
// 224.085 us; speedup vs baseline: 3.8591x; 1.1747x over previous
//
#include <hip/hip_runtime.h>
#include <math.h>

#define LLEN 4096
#define CCH 128
#define DI 384
#define NST 4
#define SBN 6        // 3 directions x B=2
#define NB 2
#define FCH 512
#define NCHUNK 128
#define TSTEP 32

typedef short bf16x8 __attribute__((ext_vector_type(8)));
typedef short bf16x4 __attribute__((ext_vector_type(4)));
typedef float f32x4 __attribute__((ext_vector_type(4)));

__device__ __forceinline__ float wave_sum(float v) {
#pragma unroll
    for (int o = 32; o > 0; o >>= 1) v += __shfl_xor(v, o);
    return v;
}

__device__ __forceinline__ short f2bf(float f) {
    unsigned int u = __float_as_uint(f);
    unsigned int r = (u + 0x7fffu + ((u >> 16) & 1u)) >> 16;
    return (short)r;
}
__device__ __forceinline__ float bf2f(short s) {
    return __uint_as_float(((unsigned int)(unsigned short)s) << 16);
}

// ---------------- weight bf16 pool offsets (elements) ----------------
#define OFF_IN  0         // in_w            768x128
#define OFF_BC  98304     // xp_w rows 128..135   8x384
#define OFF_DTC 101376    // composed dt_w @ xp_w[:128]  384x384
#define OFF_OUT 248832    // out_w           128x384
#define OFF_FC1 297984    // fc1_w           512x128
#define OFF_FC2 363520    // fc2_w           128x512
#define OFF_END 429056

__global__ __launch_bounds__(256) void convert_weights(const float* __restrict__ in_w,
                                                       const float* __restrict__ xp_w,
                                                       const float* __restrict__ out_w,
                                                       const float* __restrict__ fc1_w,
                                                       const float* __restrict__ fc2_w,
                                                       short* __restrict__ wb)
{
    int i = blockIdx.x * 256 + threadIdx.x;
    float v;
    if (i < OFF_BC) v = in_w[i];
    else if (i < OFF_DTC) v = xp_w[128 * 384 + (i - OFF_BC)];
    else if (i < OFF_OUT) return;                      // composed region (compose_dtw writes it)
    else if (i < OFF_FC1) v = out_w[i - OFF_OUT];
    else if (i < OFF_FC2) v = fc1_w[i - OFF_FC1];
    else if (i < OFF_END) v = fc2_w[i - OFF_FC2];
    else return;
    wb[i] = f2bf(v);
}

// Wc[j,k] = sum_n dt_w[j,n] * xp_w[n,k]   (j,k in [0,384), n in [0,128))
__global__ __launch_bounds__(256) void compose_dtw(const float* __restrict__ dt_w,
                                                   const float* __restrict__ xp_w,
                                                   short* __restrict__ wc)
{
    int k = blockIdx.x * 16 + threadIdx.x;
    int j = blockIdx.y * 16 + threadIdx.y;
    float acc = 0.f;
#pragma unroll 8
    for (int n = 0; n < 128; n++)
        acc += dt_w[j * 128 + n] * xp_w[n * 384 + k];
    wc[j * 384 + k] = f2bf(acc);
}

// ---------------- LayerNorm over C=128, building x_in on the fly, bf16 out ----------------
__global__ __launch_bounds__(64) void prep_ln1(const float* __restrict__ x,
                                               const int* __restrict__ ridx,
                                               const float* __restrict__ g,
                                               const float* __restrict__ b,
                                               short* __restrict__ xn)
{
    int r = blockIdx.x;
    int sb = r / LLEN, l = r % LLEN;
    int s = sb >> 1, bb = sb & 1;
    int srcl = (s == 0) ? l : (s == 1 ? (LLEN - 1 - l) : ridx[l]);
    const float* src = x + ((size_t)bb * LLEN + srcl) * CCH;
    int lane = threadIdx.x;
    float v0 = src[lane], v1 = src[lane + 64];
    float m = wave_sum(v0 + v1) * (1.f / 128.f);
    float d0 = v0 - m, d1 = v1 - m;
    float var = wave_sum(d0 * d0 + d1 * d1) * (1.f / 128.f);
    float rstd = rsqrtf(var + 1e-5f);
    short* dst = xn + (size_t)r * CCH;
    dst[lane]      = f2bf(d0 * rstd * g[lane]      + b[lane]);
    dst[lane + 64] = f2bf(d1 * rstd * g[lane + 64] + b[lane + 64]);
}

// ---------------- narrow MFMA GEMM (64x64 tile) — only for the N=8 B/C projection ----------------
template<int EPI>
__global__ __launch_bounds__(256) void gemm_mfma(const short* __restrict__ A, int lda,
                                                 const short* __restrict__ W, int ldw, int N,
                                                 const float* __restrict__ bias,
                                                 const float* __restrict__ res, int ldr,
                                                 float* __restrict__ C0,
                                                 short* __restrict__ Cb, int ldc,
                                                 int M, int Kd)
{
    __shared__ short Als[64 * 72];
    __shared__ short Wls[64 * 72];
    int tid = threadIdx.x;
    int wid = tid >> 6, lane = tid & 63;
    int wm = wid >> 1, wn = wid & 1;
    int l15 = lane & 15, l4 = lane >> 4;
    int bm = blockIdx.x * 64, bn = blockIdx.y * 64;
    int srow = tid >> 3, scol = (tid & 7) * 8;
    f32x4 acc[2][2] = {};
    for (int k0 = 0; k0 < Kd; k0 += 64) {
        bf16x8 av0 = *(const bf16x8*)&A[(size_t)(bm + srow) * lda + k0 + scol];
        bf16x8 av1 = *(const bf16x8*)&A[(size_t)(bm + srow + 32) * lda + k0 + scol];
        int n0 = bn + srow, n1 = bn + srow + 32;
        bf16x8 wv0 = {}; bf16x8 wv1 = {};
        if (n0 < N) wv0 = *(const bf16x8*)&W[(size_t)n0 * ldw + k0 + scol];
        if (n1 < N) wv1 = *(const bf16x8*)&W[(size_t)n1 * ldw + k0 + scol];
        __syncthreads();
        *(bf16x8*)&Als[srow * 72 + scol] = av0;
        *(bf16x8*)&Als[(srow + 32) * 72 + scol] = av1;
        *(bf16x8*)&Wls[srow * 72 + scol] = wv0;
        *(bf16x8*)&Wls[(srow + 32) * 72 + scol] = wv1;
        __syncthreads();
#pragma unroll
        for (int ks = 0; ks < 2; ks++) {
            bf16x8 af[2], bw[2];
#pragma unroll
            for (int f = 0; f < 2; f++) {
                af[f] = *(const bf16x8*)&Als[(wm * 32 + f * 16 + l15) * 72 + ks * 32 + l4 * 8];
                bw[f] = *(const bf16x8*)&Wls[(wn * 32 + f * 16 + l15) * 72 + ks * 32 + l4 * 8];
            }
#pragma unroll
            for (int i = 0; i < 2; i++)
#pragma unroll
                for (int j = 0; j < 2; j++)
                    acc[i][j] = __builtin_amdgcn_mfma_f32_16x16x32_bf16(af[i], bw[j], acc[i][j], 0, 0, 0);
        }
    }
#pragma unroll
    for (int i = 0; i < 2; i++) {
        int row0 = bm + wm * 32 + i * 16 + l4 * 4;
#pragma unroll
        for (int j = 0; j < 2; j++) {
            int col = bn + wn * 32 + j * 16 + l15;
            if (col < N) {
#pragma unroll
                for (int r = 0; r < 4; r++) {
                    float v = acc[i][j][r];
                    C0[(size_t)(row0 + r) * ldc + col] = v;
                }
            }
        }
    }
}

// ---------------- wide MFMA GEMM (64x128 tile, N multiple of 128) ----------------
// EPI: 0=f32  2=bias+softplus bf16  3=bias+residual f32  5=bf16  6=bias bf16
template<int EPI>
__global__ __launch_bounds__(256) void gemm_w(const short* __restrict__ A, int lda,
                                              const short* __restrict__ W, int ldw,
                                              const float* __restrict__ bias,
                                              const float* __restrict__ res, int ldr,
                                              float* __restrict__ C0,
                                              short* __restrict__ Cb, int ldc,
                                              int Kd)
{
    __shared__ short Als[64 * 72];
    __shared__ short Wls[128 * 72];
    int tid = threadIdx.x;
    int wid = tid >> 6, lane = tid & 63;
    int wm = wid >> 1, wn = wid & 1;
    int l15 = lane & 15, l4 = lane >> 4;
    int bm = blockIdx.x * 64, bn = blockIdx.y * 128;
    int srow = tid >> 3, scol = (tid & 7) * 8;
    f32x4 acc[2][4] = {};
    for (int k0 = 0; k0 < Kd; k0 += 64) {
        bf16x8 av0 = *(const bf16x8*)&A[(size_t)(bm + srow) * lda + k0 + scol];
        bf16x8 av1 = *(const bf16x8*)&A[(size_t)(bm + srow + 32) * lda + k0 + scol];
        bf16x8 wv[4];
#pragma unroll
        for (int q = 0; q < 4; q++)
            wv[q] = *(const bf16x8*)&W[(size_t)(bn + srow + 32 * q) * ldw + k0 + scol];
        __syncthreads();
        *(bf16x8*)&Als[srow * 72 + scol] = av0;
        *(bf16x8*)&Als[(srow + 32) * 72 + scol] = av1;
#pragma unroll
        for (int q = 0; q < 4; q++)
            *(bf16x8*)&Wls[(srow + 32 * q) * 72 + scol] = wv[q];
        __syncthreads();
#pragma unroll
        for (int ks = 0; ks < 2; ks++) {
            bf16x8 af[2], bw[4];
#pragma unroll
            for (int f = 0; f < 2; f++)
                af[f] = *(const bf16x8*)&Als[(wm * 32 + f * 16 + l15) * 72 + ks * 32 + l4 * 8];
#pragma unroll
            for (int j = 0; j < 4; j++)
                bw[j] = *(const bf16x8*)&Wls[(wn * 64 + j * 16 + l15) * 72 + ks * 32 + l4 * 8];
#pragma unroll
            for (int i = 0; i < 2; i++)
#pragma unroll
                for (int j = 0; j < 4; j++)
                    acc[i][j] = __builtin_amdgcn_mfma_f32_16x16x32_bf16(af[i], bw[j], acc[i][j], 0, 0, 0);
        }
    }
#pragma unroll
    for (int i = 0; i < 2; i++) {
        int row0 = bm + wm * 32 + i * 16 + l4 * 4;
#pragma unroll
        for (int j = 0; j < 4; j++) {
            int col = bn + wn * 64 + j * 16 + l15;
            float bv = (EPI == 2 || EPI == 3 || EPI == 6) ? bias[col] : 0.f;
#pragma unroll
            for (int r = 0; r < 4; r++) {
                float v = acc[i][j][r] + bv;
                if (EPI == 2) v = (v > 20.f) ? v : __logf(1.f + __expf(v));
                if (EPI == 3) v += res[(size_t)(row0 + r) * ldr + col];
                if (EPI == 2 || EPI == 5 || EPI == 6)
                    Cb[(size_t)(row0 + r) * ldc + col] = f2bf(v);
                else
                    C0[(size_t)(row0 + r) * ldc + col] = v;
            }
        }
    }
}

// ---------------- depthwise causal conv K=4 + bias + SiLU: sliding-window vectorized ----------------
// thread: d-chunk (8 ch) x 8 consecutive l. 48 threads cover one row contiguously.
__global__ __launch_bounds__(192) void dwconv_silu_v2(const short* __restrict__ hg,
                                                      const float* __restrict__ cw,
                                                      const float* __restrict__ cb,
                                                      short* __restrict__ ub)
{
    int t = threadIdx.x;
    int c = t % 48, rs = t / 48;
    int blk = blockIdx.x;            // 768 blocks: 6 sb x 128
    int sb = blk >> 7;
    int l0 = ((blk & 127) << 5) + rs * 8;
    int d0 = c * 8;
    float w0[8], w1[8], w2[8], w3[8], bs[8];
#pragma unroll
    for (int e = 0; e < 8; e++) {
        int d = d0 + e;
        bs[e] = cb[d];
        w0[e] = cw[d * 4 + 0]; w1[e] = cw[d * 4 + 1];
        w2[e] = cw[d * 4 + 2]; w3[e] = cw[d * 4 + 3];
    }
    float r0[8], r1[8], r2[8];
#pragma unroll
    for (int e = 0; e < 8; e++) { r0[e] = 0.f; r1[e] = 0.f; r2[e] = 0.f; }
    if (l0 - 3 >= 0) { bf16x8 v = *(const bf16x8*)&hg[(size_t)(sb * LLEN + l0 - 3) * 768 + d0];
#pragma unroll
        for (int e = 0; e < 8; e++) r0[e] = bf2f(v[e]); }
    if (l0 - 2 >= 0) { bf16x8 v = *(const bf16x8*)&hg[(size_t)(sb * LLEN + l0 - 2) * 768 + d0];
#pragma unroll
        for (int e = 0; e < 8; e++) r1[e] = bf2f(v[e]); }
    if (l0 - 1 >= 0) { bf16x8 v = *(const bf16x8*)&hg[(size_t)(sb * LLEN + l0 - 1) * 768 + d0];
#pragma unroll
        for (int e = 0; e < 8; e++) r2[e] = bf2f(v[e]); }
#pragma unroll
    for (int i = 0; i < 8; i++) {
        int row = sb * LLEN + l0 + i;
        bf16x8 v = *(const bf16x8*)&hg[(size_t)row * 768 + d0];
        float r3[8];
#pragma unroll
        for (int e = 0; e < 8; e++) r3[e] = bf2f(v[e]);
        bf16x8 ov;
#pragma unroll
        for (int e = 0; e < 8; e++) {
            float a = bs[e] + w0[e] * r0[e] + w1[e] * r1[e] + w2[e] * r2[e] + w3[e] * r3[e];
            ov[e] = f2bf(a * __builtin_amdgcn_rcpf(1.f + __expf(-a)));
        }
        *(bf16x8*)&ub[(size_t)row * DI + d0] = ov;
#pragma unroll
        for (int e = 0; e < 8; e++) { r0[e] = r1[e]; r1[e] = r2[e]; r2[e] = r3[e]; }
    }
}

// ---------------- chunked selective scan ----------------
__global__ __launch_bounds__(DI) void scan_phaseA(const short* __restrict__ dt,
                                                  const float* __restrict__ bc,
                                                  const short* __restrict__ u,
                                                  const float* __restrict__ A_log,
                                                  float* __restrict__ P, float* __restrict__ S)
{
    int d = threadIdx.x;
    int chunk = blockIdx.x, sb = blockIdx.y;
    float a[NST];
#pragma unroll
    for (int n = 0; n < NST; n++) a[n] = -__expf(A_log[d * NST + n]);
    float s[NST] = {0.f, 0.f, 0.f, 0.f}, p[NST] = {1.f, 1.f, 1.f, 1.f};
    int base = sb * LLEN + chunk * TSTEP;
    for (int t = 0; t < TSTEP; t++) {
        int row = base + t;
        float dtv = bf2f(dt[(size_t)row * DI + d]);
        float uv = bf2f(u[(size_t)row * DI + d]);
        float dtu = dtv * uv;
#pragma unroll
        for (int n = 0; n < NST; n++) {
            float dA = __expf(dtv * a[n]);
            float Bv = bc[(size_t)row * 8 + n];
            s[n] = dA * s[n] + dtu * Bv;
            p[n] *= dA;
        }
    }
    int idx = ((sb * NCHUNK + chunk) * DI + d) * NST;
#pragma unroll
    for (int n = 0; n < NST; n++) { P[idx + n] = p[n]; S[idx + n] = s[n]; }
}

__global__ __launch_bounds__(256) void scan_phaseB(const float* __restrict__ P,
                                                   const float* __restrict__ S,
                                                   float* __restrict__ I)
{
    int gid = blockIdx.x * 256 + threadIdx.x;
    if (gid >= SBN * DI * NST) return;
    int dn = gid % (DI * NST);
    int sb = gid / (DI * NST);
    float st = 0.f;
#pragma unroll 4
    for (int c = 0; c < NCHUNK; c++) {
        int idx = (sb * NCHUNK + c) * DI * NST + dn;
        I[idx] = st;
        st = P[idx] * st + S[idx];
    }
}

__global__ __launch_bounds__(DI) void scan_phaseC(const short* __restrict__ dt,
                                                  const float* __restrict__ bc,
                                                  const short* __restrict__ u,
                                                  const float* __restrict__ A_log,
                                                  const float* __restrict__ Dp,
                                                  const short* __restrict__ hg,
                                                  const float* __restrict__ I,
                                                  short* __restrict__ ymix)
{
    int d = threadIdx.x;
    int chunk = blockIdx.x, sb = blockIdx.y;
    float a[NST];
#pragma unroll
    for (int n = 0; n < NST; n++) a[n] = -__expf(A_log[d * NST + n]);
    int idx = ((sb * NCHUNK + chunk) * DI + d) * NST;
    float s[NST];
#pragma unroll
    for (int n = 0; n < NST; n++) s[n] = I[idx + n];
    float Dv = Dp[d];
    int base = sb * LLEN + chunk * TSTEP;
    for (int t = 0; t < TSTEP; t++) {
        int row = base + t;
        float dtv = bf2f(dt[(size_t)row * DI + d]);
        float uv = bf2f(u[(size_t)row * DI + d]);
        float dtu = dtv * uv;
        float y = 0.f;
#pragma unroll
        for (int n = 0; n < NST; n++) {
            float dA = __expf(dtv * a[n]);
            float Bv = bc[(size_t)row * 8 + n];
            float Cv = bc[(size_t)row * 8 + 4 + n];
            s[n] = dA * s[n] + dtu * Bv;
            y += s[n] * Cv;
        }
        float gt = bf2f(hg[(size_t)row * 768 + 384 + d]);
        float sg = gt * __builtin_amdgcn_rcpf(1.f + __expf(-gt));
        ymix[(size_t)row * DI + d] = f2bf((y + uv * Dv) * sg);
    }
}

// ---------------- column means of y6 per (sb) ----------------
__global__ __launch_bounds__(256) void colmeans(const float* __restrict__ y6, float* __restrict__ means)
{
    int sb = blockIdx.x, rc = blockIdx.y;
    int c = threadIdx.x & 127, r0 = threadIdx.x >> 7;
    float ssum = 0.f;
    for (int r = rc * 256 + r0; r < rc * 256 + 256; r += 2)
        ssum += y6[((size_t)sb * LLEN + r) * CCH + c];
    __shared__ float red[128];
    if (r0) red[c] = ssum;
    __syncthreads();
    if (!r0) atomicAdd(&means[sb * CCH + c], ssum + red[c]);
}

__global__ __launch_bounds__(384) void gate_softmax(const float* __restrict__ means,
                                                    const float* __restrict__ gw,
                                                    float* __restrict__ g)
{
    int lane = threadIdx.x & 63, p = threadIdx.x >> 6;
    int bb = p / 3, j = p % 3;
    float part = 0.f;
    for (int i = lane; i < 384; i += 64) {
        int s = i >> 7, c = i & 127;
        part += means[(s * 2 + bb) * 128 + c] * (1.f / 4096.f) * gw[j * 384 + i];
    }
    part = wave_sum(part);
    __shared__ float lg[6];
    if (lane == 0) lg[p] = part;
    __syncthreads();
    if (threadIdx.x < 2) {
        int b2 = threadIdx.x;
        float a0 = lg[b2 * 3], a1 = lg[b2 * 3 + 1], a2 = lg[b2 * 3 + 2];
        float mx = fmaxf(a0, fmaxf(a1, a2));
        float e0 = __expf(a0 - mx), e1 = __expf(a1 - mx), e2 = __expf(a2 - mx);
        float inv = __builtin_amdgcn_rcpf(e0 + e1 + e2);
        g[b2 * 3] = e0 * inv; g[b2 * 3 + 1] = e1 * inv; g[b2 * 3 + 2] = e2 * inv;
    }
}

__global__ void make_inv(const int* __restrict__ ridx, int* __restrict__ inv)
{
    int l = blockIdx.x * blockDim.x + threadIdx.x;
    if (l < LLEN) inv[ridx[l]] = l;
}

// combine 3 directions + residual + LayerNorm2 (x1 f32, xn2 bf16)
__global__ __launch_bounds__(64) void combine_ln2(const float* __restrict__ x,
                                                  const float* __restrict__ y6,
                                                  const float* __restrict__ g,
                                                  const int* __restrict__ inv,
                                                  const float* __restrict__ n2g,
                                                  const float* __restrict__ n2b,
                                                  float* __restrict__ x1,
                                                  short* __restrict__ xn2)
{
    int r = blockIdx.x;
    int bb = r / LLEN, l = r % LLEN;
    int lane = threadIdx.x;
    float g0 = g[bb * 3 + 0], g1 = g[bb * 3 + 1], g2 = g[bb * 3 + 2];
    int il = inv[l];
    size_t fo = ((size_t)(0 + bb) * LLEN + l) * CCH;
    size_t ro = ((size_t)(2 + bb) * LLEN + (LLEN - 1 - l)) * CCH;
    size_t so = ((size_t)(4 + bb) * LLEN + il) * CCH;
    size_t xo = ((size_t)bb * LLEN + l) * CCH;
    float v0 = x[xo + lane]      + g0 * y6[fo + lane]      + g1 * y6[ro + lane]      + g2 * y6[so + lane];
    float v1 = x[xo + lane + 64] + g0 * y6[fo + lane + 64] + g1 * y6[ro + lane + 64] + g2 * y6[so + lane + 64];
    float m = wave_sum(v0 + v1) * (1.f / 128.f);
    float d0 = v0 - m, d1 = v1 - m;
    float var = wave_sum(d0 * d0 + d1 * d1) * (1.f / 128.f);
    float rstd = rsqrtf(var + 1e-5f);
    x1[xo + lane] = v0; x1[xo + lane + 64] = v1;
    xn2[xo + lane]      = f2bf(d0 * rstd * n2g[lane]      + n2b[lane]);
    xn2[xo + lane + 64] = f2bf(d1 * rstd * n2g[lane + 64] + n2b[lane + 64]);
}

// ---------------- 3x3 depthwise conv + exact GeLU: sliding-window vectorized ----------------
// thread: f-chunk (4 ch) x 16 consecutive w; 128 threads cover a pixel's 512 f contiguously.
__global__ __launch_bounds__(256) void peconv_gelu_v2(const short* __restrict__ t,
                                                      const float* __restrict__ pw,
                                                      const float* __restrict__ pb,
                                                      short* __restrict__ t2)
{
    int tid = threadIdx.x;
    int fc = tid & 127;       // f-chunk of 4
    int wsr = tid >> 7;       // 0..1
    int blk = blockIdx.x;     // 256 = bb(2) x h(64) x whalf(2)
    int whalf = blk & 1, h = (blk >> 1) & 63, bb = blk >> 7;
    int w0 = whalf * 32 + wsr * 16;
    int f0 = fc * 4;
    float wt[9][4], bias4[4];
#pragma unroll
    for (int e = 0; e < 4; e++) {
        bias4[e] = pb[f0 + e];
#pragma unroll
        for (int k = 0; k < 9; k++) wt[k][e] = pw[(f0 + e) * 9 + k];
    }
    size_t base = (size_t)bb * 4096 * FCH;
    // window cols: cm1(w-1), cc(w), cn(w+1); rows rr in {-1,0,1}
    float cm1[3][4], cc[3][4], cn[3][4];
#pragma unroll
    for (int rr = 0; rr < 3; rr++)
#pragma unroll
        for (int e = 0; e < 4; e++) { cm1[rr][e] = 0.f; cc[rr][e] = 0.f; }
    // init: col w0-1 and w0
#pragma unroll
    for (int rr = 0; rr < 3; rr++) {
        int hh = h + rr - 1;
        if (hh >= 0 && hh < 64) {
            if (w0 - 1 >= 0) {
                bf16x4 v = *(const bf16x4*)&t[base + ((size_t)hh * 64 + (w0 - 1)) * FCH + f0];
#pragma unroll
                for (int e = 0; e < 4; e++) cm1[rr][e] = bf2f(v[e]);
            }
            bf16x4 v = *(const bf16x4*)&t[base + ((size_t)hh * 64 + w0) * FCH + f0];
#pragma unroll
            for (int e = 0; e < 4; e++) cc[rr][e] = bf2f(v[e]);
        }
    }
#pragma unroll
    for (int i = 0; i < 16; i++) {
        int w = w0 + i;
        // load col w+1
#pragma unroll
        for (int rr = 0; rr < 3; rr++) {
#pragma unroll
            for (int e = 0; e < 4; e++) cn[rr][e] = 0.f;
            int hh = h + rr - 1;
            if (hh >= 0 && hh < 64 && w + 1 < 64) {
                bf16x4 v = *(const bf16x4*)&t[base + ((size_t)hh * 64 + (w + 1)) * FCH + f0];
#pragma unroll
                for (int e = 0; e < 4; e++) cn[rr][e] = bf2f(v[e]);
            }
        }
        bf16x4 ov;
#pragma unroll
        for (int e = 0; e < 4; e++) {
            float acc = bias4[e];
#pragma unroll
            for (int rr = 0; rr < 3; rr++) {
                acc += wt[rr * 3 + 0][e] * cm1[rr][e];
                acc += wt[rr * 3 + 1][e] * cc[rr][e];
                acc += wt[rr * 3 + 2][e] * cn[rr][e];
            }
            ov[e] = f2bf(0.5f * acc * (1.f + erff(acc * 0.70710678118654752f)));
        }
        *(bf16x4*)&t2[base + ((size_t)h * 64 + w) * FCH + f0] = ov;
#pragma unroll
        for (int rr = 0; rr < 3; rr++)
#pragma unroll
            for (int e = 0; e < 4; e++) { cm1[rr][e] = cc[rr][e]; cc[rr][e] = cn[rr][e]; }
    }
}

extern "C" void kernel_launch(void* const* d_in, const int* in_sizes, int n_in,
                              void* d_out, int out_size, void* d_ws, size_t ws_size,
                              hipStream_t stream)
{
    (void)in_sizes; (void)n_in; (void)ws_size; (void)out_size;
    const float* x      = (const float*)d_in[0];
    const int*   ridx   = (const int*)d_in[1];
    const float* n1g    = (const float*)d_in[4];
    const float* n1b    = (const float*)d_in[5];
    const float* in_w   = (const float*)d_in[6];
    const float* conv_w = (const float*)d_in[7];
    const float* conv_b = (const float*)d_in[8];
    const float* xp_w   = (const float*)d_in[9];
    const float* dt_w   = (const float*)d_in[10];
    const float* dt_b   = (const float*)d_in[11];
    const float* A_log  = (const float*)d_in[12];
    const float* Dp     = (const float*)d_in[13];
    const float* out_w  = (const float*)d_in[14];
    const float* n2g    = (const float*)d_in[15];
    const float* n2b    = (const float*)d_in[16];
    const float* gate_w = (const float*)d_in[17];
    const float* fc1_w  = (const float*)d_in[18];
    const float* fc1_b  = (const float*)d_in[19];
    const float* pe_w   = (const float*)d_in[20];
    const float* pe_b   = (const float*)d_in[21];
    const float* fc2_w  = (const float*)d_in[22];
    const float* fc2_b  = (const float*)d_in[23];
    float* out = (float*)d_out;

    float* ws = (float*)d_ws;
    short* wb   = (short*)ws;                       // 429,056 bf16 (215,040 f32 slots)
    float* regA = ws + 215040;                      // xn(bf16) -> P(f32) -> tbuf(bf16)   [2,097,152 f32]
    float* regB = regA + 2097152;                   // hg(bf16) -> {y6,x1,xn2,t2}         [9,437,184 f32]
    float* regC = regB + 9437184;                   // ub(bf16)                           [4,718,592 f32]
    float* regD = regC + 4718592;                   // ymix(bf16)                         [4,718,592 f32]
    float* regE = regD + 4718592;                   // dtb(bf16)                          [4,718,592 f32]
    float* regF = regE + 4718592;                   // S, I (f32)                         [2,359,296 f32]
    float* regG = regF + 2359296;                   // xpbc (f32)                         [196,608 f32]
    float* smallb = regG + 196608;

    short* xn   = (short*)regA;
    float* P    = regA;
    short* tbuf = (short*)regA;
    short* hg   = (short*)regB;
    float* y6   = regB;
    float* x1   = regB + 3145728;
    short* xn2  = (short*)(regB + 4194304);
    short* t2   = (short*)(regB + 4718592);
    short* ub   = (short*)regC;
    short* ymix = (short*)regD;
    short* dtb  = (short*)regE;
    float* S    = regF;
    float* I    = regF + 1179648;
    float* xpbc = regG;
    float* means = smallb;
    float* gbuf  = smallb + 768;
    int*   invb  = (int*)(gbuf + 8);

    const int M6 = SBN * LLEN;   // 24576
    const int M2 = NB * LLEN;    // 8192

    convert_weights<<<(OFF_END + 255) / 256, 256, 0, stream>>>(in_w, xp_w, out_w, fc1_w, fc2_w, wb);
    compose_dtw<<<dim3(24, 24), dim3(16, 16), 0, stream>>>(dt_w, xp_w, wb + OFF_DTC);
    prep_ln1<<<M6, 64, 0, stream>>>(x, ridx, n1g, n1b, xn);
    // fused in_proj: [h | gate] N=768, bf16 out
    gemm_w<5><<<dim3(M6 / 64, 6), 256, 0, stream>>>(xn, CCH, wb + OFF_IN, CCH, nullptr, nullptr, 0, nullptr, hg, 768, CCH);
    dwconv_silu_v2<<<768, 192, 0, stream>>>(hg, conv_w, conv_b, ub);
    // B/C projection: N=8, f32 out
    gemm_mfma<0><<<dim3(M6 / 64, 1), 256, 0, stream>>>(ub, DI, wb + OFF_BC, DI, 8, nullptr, nullptr, 0, xpbc, nullptr, 8, M6, DI);
    // composed dt projection + softplus, bf16 out
    gemm_w<2><<<dim3(M6 / 64, 3), 256, 0, stream>>>(ub, DI, wb + OFF_DTC, DI, dt_b, nullptr, 0, nullptr, dtb, DI, DI);
    // selective scan
    scan_phaseA<<<dim3(NCHUNK, SBN), DI, 0, stream>>>(dtb, xpbc, ub, A_log, P, S);
    scan_phaseB<<<(SBN * DI * NST + 255) / 256, 256, 0, stream>>>(P, S, I);
    scan_phaseC<<<dim3(NCHUNK, SBN), DI, 0, stream>>>(dtb, xpbc, ub, A_log, Dp, hg, I, ymix);
    // out_proj
    gemm_w<0><<<dim3(M6 / 64, 1), 256, 0, stream>>>(ymix, DI, wb + OFF_OUT, DI, nullptr, nullptr, 0, y6, nullptr, CCH, DI);
    // direction gating
    hipMemsetAsync(means, 0, 768 * sizeof(float), stream);
    colmeans<<<dim3(SBN, 16), 256, 0, stream>>>(y6, means);
    gate_softmax<<<1, 384, 0, stream>>>(means, gate_w, gbuf);
    make_inv<<<LLEN / 256, 256, 0, stream>>>(ridx, invb);
    combine_ln2<<<M2, 64, 0, stream>>>(x, y6, gbuf, invb, n2g, n2b, x1, xn2);
    // MixFFN
    gemm_w<6><<<dim3(M2 / 64, 4), 256, 0, stream>>>(xn2, CCH, wb + OFF_FC1, CCH, fc1_b, nullptr, 0, nullptr, tbuf, FCH, CCH);
    peconv_gelu_v2<<<256, 256, 0, stream>>>(tbuf, pe_w, pe_b, t2);
    gemm_w<3><<<dim3(M2 / 64, 1), 256, 0, stream>>>(t2, FCH, wb + OFF_FC2, FCH, fc2_b, x1, CCH, out, nullptr, CCH, FCH);
}